// Round 1
// baseline (164.779 us; speedup 1.0000x reference)
//
#include <hip/hip_runtime.h>
#include <hip/hip_bf16.h>

// AutoCorrelation (Autoformer): FFT-based circular cross-correlation,
// top-8 delays, softmax weights, rolled-value aggregation.
// B=8, L=4096, H=8, D=32, K=8. Layout [B,L,H,D]: idx = b*1048576 + l*256 + h*32 + d.
//
// ws layout (floats):
//   [0,       131136)  spd_re  (64*2049)   -- accumulated over d via atomics
//   [131136,  262272)  spd_im
//   [262272,  262784)  weights (64*8)
//   [262784,  263296)  delays  (64*8, int)
//   [263296,  267392)  tw_re   (4096)      -- e^{-2*pi*i*m/4096} table
//   [267392,  271488)  tw_im
// total ~1.04 MB

#define NFFT 4096
#define NTH  256

__global__ __launch_bounds__(256) void twiddle_init_kernel(float* twr, float* twi) {
    int m = blockIdx.x * 256 + threadIdx.x;             // 16 blocks -> m in [0,4096)
    float ang = 6.2831853071795864769f * (float)m / 4096.0f;
    twr[m] = cosf(ang);
    twi[m] = -sinf(ang);                                // forward twiddle e^{-i*ang}
}

// One Stockham radix-4 stage: src -> dst. DIR=-1 forward, +1 inverse.
// j in [0,1024): v[r]=src[j+r*1024]*w^r, w=e^{DIR*2*pi*i*(j%NS)/(4*NS)};
// 4-pt DFT; dst[(j/NS)*4*NS + j%NS + r*NS] = X[r].
template<int DIR, int NS>
__device__ inline void fft_stage(const float* __restrict__ sr, const float* __restrict__ si,
                                 float* __restrict__ dr, float* __restrict__ di,
                                 const float* __restrict__ twr, const float* __restrict__ twi,
                                 int tid) {
#pragma unroll
    for (int t = 0; t < 4; ++t) {
        int j  = tid + t * NTH;                         // [0, 1024)
        int jm = j & (NS - 1);
        float v0r = sr[j],        v0i = si[j];
        float v1r = sr[j + 1024], v1i = si[j + 1024];
        float v2r = sr[j + 2048], v2i = si[j + 2048];
        float v3r = sr[j + 3072], v3i = si[j + 3072];
        if (NS > 1) {
            int m = jm * (1024 / NS);                   // twiddle exponent (r=1), 3m < 4096
            float c1 = twr[m], s1 = twi[m];
            if (DIR > 0) s1 = -s1;                      // conjugate for inverse
            float c2 = c1 * c1 - s1 * s1;               // w^2
            float s2 = 2.0f * c1 * s1;
            float c3 = c2 * c1 - s2 * s1;               // w^3
            float s3 = c2 * s1 + s2 * c1;
            float r;
            r = v1r * c1 - v1i * s1; v1i = v1r * s1 + v1i * c1; v1r = r;
            r = v2r * c2 - v2i * s2; v2i = v2r * s2 + v2i * c2; v2r = r;
            r = v3r * c3 - v3i * s3; v3i = v3r * s3 + v3i * c3; v3r = r;
        }
        float t0r = v0r + v2r, t0i = v0i + v2i;
        float t1r = v0r - v2r, t1i = v0i - v2i;
        float t2r = v1r + v3r, t2i = v1i + v3i;
        float t3r = v1r - v3r, t3i = v1i - v3i;
        float x0r = t0r + t2r, x0i = t0i + t2i;
        float x2r = t0r - t2r, x2i = t0i - t2i;
        float x1r, x1i, x3r, x3i;
        if (DIR < 0) {                                  // forward: X1 = t1 - i*t3
            x1r = t1r + t3i; x1i = t1i - t3r;
            x3r = t1r - t3i; x3i = t1i + t3r;
        } else {                                        // inverse: X1 = t1 + i*t3
            x1r = t1r - t3i; x1i = t1i + t3r;
            x3r = t1r + t3i; x3i = t1i - t3r;
        }
        int idxD = (j / NS) * (NS * 4) + jm;
        dr[idxD]          = x0r; di[idxD]          = x0i;
        dr[idxD + NS]     = x1r; di[idxD + NS]     = x1i;
        dr[idxD + 2 * NS] = x2r; di[idxD + 2 * NS] = x2i;
        dr[idxD + 3 * NS] = x3r; di[idxD + 3 * NS] = x3i;
    }
}

// 6 radix-4 stages, ping-pong A->B->A->...; result lands back in A (natural order).
template<int DIR>
__device__ inline void fft4096(float* Ar, float* Ai, float* Br, float* Bi,
                               const float* twr, const float* twi, int tid) {
    fft_stage<DIR, 1>(Ar, Ai, Br, Bi, twr, twi, tid);    __syncthreads();
    fft_stage<DIR, 4>(Br, Bi, Ar, Ai, twr, twi, tid);    __syncthreads();
    fft_stage<DIR, 16>(Ar, Ai, Br, Bi, twr, twi, tid);   __syncthreads();
    fft_stage<DIR, 64>(Br, Bi, Ar, Ai, twr, twi, tid);   __syncthreads();
    fft_stage<DIR, 256>(Ar, Ai, Br, Bi, twr, twi, tid);  __syncthreads();
    fft_stage<DIR, 1024>(Br, Bi, Ar, Ai, twr, twi, tid); __syncthreads();
}

// K1: one block per (b,h,d). Packed FFT of x=q+i*k, Hermitian unpack,
// S_d[f]=Q[f]*conj(K[f]) for f in [0,2048], atomic-accumulate over d.
__global__ __launch_bounds__(256) void fwd_spd_kernel(const float* __restrict__ q,
                                                      const float* __restrict__ k,
                                                      float* spd_re, float* spd_im,
                                                      const float* __restrict__ twr,
                                                      const float* __restrict__ twi) {
    __shared__ float Ar[NFFT], Ai[NFFT], Br[NFFT], Bi[NFFT];   // 64 KB
    int bid = blockIdx.x;                 // [0,2048)
    int b = bid >> 8;
    int h = (bid >> 5) & 7;
    int d = bid & 31;
    int tid = threadIdx.x;
    size_t base = (size_t)b * 1048576u + (size_t)h * 32u + (size_t)d;
#pragma unroll
    for (int t = 0; t < 16; ++t) {
        int n = tid + t * 256;
        Ar[n] = q[base + (size_t)n * 256u];   // x.re = q
        Ai[n] = k[base + (size_t)n * 256u];   // x.im = k
    }
    __syncthreads();
    fft4096<-1>(Ar, Ai, Br, Bi, twr, twi, tid);
    float* sre = spd_re + (size_t)(b * 8 + h) * 2049u;
    float* sim = spd_im + (size_t)(b * 8 + h) * 2049u;
    for (int f = tid; f <= 2048; f += 256) {
        float a1 = Ar[f], b1 = Ai[f];
        int mm = (4096 - f) & 4095;
        float a2 = Ar[mm], b2 = Ai[mm];
        // 2Q = (a1+a2) + i(b1-b2); 2conj(K) = (b1+b2) + i(a1-a2)
        float qr = a1 + a2, qi = b1 - b2;
        float kr = b1 + b2, ki = a1 - a2;
        atomicAdd(&sre[f], 0.25f * (qr * kr - qi * ki));
        atomicAdd(&sim[f], 0.25f * (qr * ki + qi * kr));
    }
}

// K2: one block per (b,h). Mirror Hermitian spectrum, inverse FFT (x 1/N),
// iterative top-8 argmax (ties -> lowest index), softmax, emit weights+delays.
__global__ __launch_bounds__(256) void ifft_topk_kernel(const float* __restrict__ spd_re,
                                                        const float* __restrict__ spd_im,
                                                        float* __restrict__ wout,
                                                        int* __restrict__ dout,
                                                        const float* __restrict__ twr,
                                                        const float* __restrict__ twi) {
    __shared__ float Ar[NFFT], Ai[NFFT], Br[NFFT], Bi[NFFT];   // 64 KB
    int bh = blockIdx.x;
    int tid = threadIdx.x;
    const float sc = 1.0f / 4096.0f;
    for (int f = tid; f <= 2048; f += 256) {
        float re = spd_re[bh * 2049 + f] * sc;
        float im = spd_im[bh * 2049 + f] * sc;
        Ar[f] = re; Ai[f] = im;
        if (f > 0 && f < 2048) { Ar[4096 - f] = re; Ai[4096 - f] = -im; }
    }
    __syncthreads();
    fft4096<1>(Ar, Ai, Br, Bi, twr, twi, tid);
    // corr[tau] = Ar[tau]. Scratch aliased into free B buffers.
    float* rv   = Br;
    int*   ri   = (int*)Bi;
    float* topv = Br + 512;
    int*   topi = ((int*)Bi) + 512;
    for (int kk = 0; kk < 8; ++kk) {
        float best = -3.0e38f; int bidx = 0;
#pragma unroll
        for (int t = 0; t < 16; ++t) {
            int f = tid + t * 256;
            float val = Ar[f];
            if (val > best) { best = val; bidx = f; }   // strict > keeps lowest f
        }
        rv[tid] = best; ri[tid] = bidx;
        __syncthreads();
        for (int off = 128; off > 0; off >>= 1) {
            if (tid < off) {
                float v2 = rv[tid + off]; int i2 = ri[tid + off];
                if (v2 > rv[tid] || (v2 == rv[tid] && i2 < ri[tid])) { rv[tid] = v2; ri[tid] = i2; }
            }
            __syncthreads();
        }
        if (tid == 0) {
            topv[kk] = rv[0]; topi[kk] = ri[0];
            Ar[ri[0]] = -3.0e38f;                       // remove winner
        }
        __syncthreads();
    }
    if (tid == 0) {
        float mx = topv[0];                             // selected descending
        float e[8], s = 0.0f;
#pragma unroll
        for (int kk = 0; kk < 8; ++kk) { e[kk] = expf(topv[kk] - mx); s += e[kk]; }
        float inv = 1.0f / s;
#pragma unroll
        for (int kk = 0; kk < 8; ++kk) {
            wout[bh * 8 + kk] = e[kk] * inv;
            dout[bh * 8 + kk] = topi[kk];
        }
    }
}

// K3: one block per (b,l); thread = h*32+d. out = sum_k w_k * v[(l+delay_k)%L].
__global__ __launch_bounds__(256) void agg_kernel(const float* __restrict__ v,
                                                  const float* __restrict__ w,
                                                  const int* __restrict__ dl,
                                                  float* __restrict__ out) {
    __shared__ float sw[64];
    __shared__ int   sd[64];
    int blk = blockIdx.x;              // b*4096 + l
    int b = blk >> 12, l = blk & 4095;
    int tid = threadIdx.x;
    if (tid < 64) {
        int h = tid >> 3, kk = tid & 7;
        sw[tid] = w[(b * 8 + h) * 8 + kk];
        sd[tid] = dl[(b * 8 + h) * 8 + kk];
    }
    __syncthreads();
    int h = tid >> 5, d = tid & 31;
    size_t vbase = (size_t)b * 1048576u + (size_t)h * 32u + (size_t)d;
    float acc = 0.0f;
#pragma unroll
    for (int kk = 0; kk < 8; ++kk) {
        float wv = sw[h * 8 + kk];
        int l2 = (l + sd[h * 8 + kk]) & 4095;
        acc += wv * v[vbase + (size_t)l2 * 256u];
    }
    out[(size_t)blk * 256u + tid] = acc;
}

extern "C" void kernel_launch(void* const* d_in, const int* in_sizes, int n_in,
                              void* d_out, int out_size, void* d_ws, size_t ws_size,
                              hipStream_t stream) {
    const float* q = (const float*)d_in[0];
    const float* k = (const float*)d_in[1];
    const float* v = (const float*)d_in[2];
    float* out = (float*)d_out;

    float* ws     = (float*)d_ws;
    float* spd_re = ws;
    float* spd_im = ws + 64 * 2049;
    float* wbuf   = ws + 2 * 64 * 2049;
    int*   dbuf   = (int*)(ws + 2 * 64 * 2049 + 512);
    float* twr    = ws + 2 * 64 * 2049 + 1024;
    float* twi    = twr + 4096;

    // zero the spd accumulators (atomic targets) each call
    hipMemsetAsync(d_ws, 0, (size_t)(2 * 64 * 2049) * sizeof(float), stream);
    twiddle_init_kernel<<<16, 256, 0, stream>>>(twr, twi);
    fwd_spd_kernel<<<2048, 256, 0, stream>>>(q, k, spd_re, spd_im, twr, twi);
    ifft_topk_kernel<<<64, 256, 0, stream>>>(spd_re, spd_im, wbuf, dbuf, twr, twi);
    agg_kernel<<<8 * 4096, 256, 0, stream>>>(v, wbuf, dbuf, out);
}

// Round 2
// 137.895 us; speedup vs baseline: 1.1950x; 1.1950x over previous
//
#include <hip/hip_runtime.h>
#include <hip/hip_bf16.h>

// AutoCorrelation (Autoformer): FFT-based circular cross-correlation,
// top-8 delays, softmax weights, rolled-value aggregation.
// B=8, L=4096, H=8, D=32, K=8. Layout [B,L,H,D]: idx = b*1048576 + l*256 + h*32 + d.
//
// R1: + transpose/pack stage (coalesced FFT loads), + PADF LDS padding
//     (bank-conflict-free radix-4 stores), fallback to strided loads if ws too small.

#define NFFT 4096
#define NTH  256
#define PADF(i) ((i) + ((i) >> 5))   // pad every 32 floats -> conflict-free strided stores
#define NP 4224                      // PADF(4095)=4222 < 4224

__global__ __launch_bounds__(256) void twiddle_init_kernel(float* twr, float* twi) {
    int m = blockIdx.x * 256 + threadIdx.x;             // 16 blocks -> m in [0,4096)
    float ang = 6.2831853071795864769f * (float)m / 4096.0f;
    twr[m] = cosf(ang);
    twi[m] = -sinf(ang);                                // forward twiddle e^{-i*ang}
}

// Transpose+pack: q,k [B, L, 256] -> xT[b, c, l] = float2(q, k), c = h*32+d.
// 64x64 tiles, LDS staged, coalesced both sides.
__global__ __launch_bounds__(256) void transpose_pack_kernel(const float* __restrict__ q,
                                                             const float* __restrict__ k,
                                                             float2* __restrict__ xT) {
    __shared__ float qs[64][65];
    __shared__ float ks[64][65];
    int bid = blockIdx.x;             // b*256 + lt*4 + ct
    int ct = bid & 3;
    int lt = (bid >> 2) & 63;
    int b  = bid >> 8;
    int tid = threadIdx.x;
    int tx = tid & 63;
    int ty = tid >> 6;                // 0..3
    int l0 = lt * 64, c0 = ct * 64;
    size_t base = (size_t)b * 1048576u;
#pragma unroll
    for (int t = 0; t < 16; ++t) {
        int row = t * 4 + ty;         // l_local
        size_t g = base + (size_t)(l0 + row) * 256u + (size_t)(c0 + tx);
        qs[row][tx] = q[g];
        ks[row][tx] = k[g];
    }
    __syncthreads();
#pragma unroll
    for (int t = 0; t < 16; ++t) {
        int cc = t * 4 + ty;          // c_local
        float2 v; v.x = qs[tx][cc]; v.y = ks[tx][cc];
        xT[((size_t)(b * 256 + c0 + cc) * 4096u) + (size_t)(l0 + tx)] = v;
    }
}

// One Stockham radix-4 stage with PADF'd LDS indices. DIR=-1 fwd, +1 inv.
template<int DIR, int NS>
__device__ inline void fft_stage(const float* __restrict__ sr, const float* __restrict__ si,
                                 float* __restrict__ dr, float* __restrict__ di,
                                 const float* __restrict__ twr, const float* __restrict__ twi,
                                 int tid) {
#pragma unroll
    for (int t = 0; t < 4; ++t) {
        int j  = tid + t * NTH;                         // [0, 1024)
        int jm = j & (NS - 1);
        float v0r = sr[PADF(j)],        v0i = si[PADF(j)];
        float v1r = sr[PADF(j + 1024)], v1i = si[PADF(j + 1024)];
        float v2r = sr[PADF(j + 2048)], v2i = si[PADF(j + 2048)];
        float v3r = sr[PADF(j + 3072)], v3i = si[PADF(j + 3072)];
        if (NS > 1) {
            int m = jm * (1024 / NS);                   // twiddle exponent (r=1)
            float c1 = twr[m], s1 = twi[m];
            if (DIR > 0) s1 = -s1;                      // conjugate for inverse
            float c2 = c1 * c1 - s1 * s1;               // w^2
            float s2 = 2.0f * c1 * s1;
            float c3 = c2 * c1 - s2 * s1;               // w^3
            float s3 = c2 * s1 + s2 * c1;
            float r;
            r = v1r * c1 - v1i * s1; v1i = v1r * s1 + v1i * c1; v1r = r;
            r = v2r * c2 - v2i * s2; v2i = v2r * s2 + v2i * c2; v2r = r;
            r = v3r * c3 - v3i * s3; v3i = v3r * s3 + v3i * c3; v3r = r;
        }
        float t0r = v0r + v2r, t0i = v0i + v2i;
        float t1r = v0r - v2r, t1i = v0i - v2i;
        float t2r = v1r + v3r, t2i = v1i + v3i;
        float t3r = v1r - v3r, t3i = v1i - v3i;
        float x0r = t0r + t2r, x0i = t0i + t2i;
        float x2r = t0r - t2r, x2i = t0i - t2i;
        float x1r, x1i, x3r, x3i;
        if (DIR < 0) {                                  // forward: X1 = t1 - i*t3
            x1r = t1r + t3i; x1i = t1i - t3r;
            x3r = t1r - t3i; x3i = t1i + t3r;
        } else {                                        // inverse: X1 = t1 + i*t3
            x1r = t1r - t3i; x1i = t1i + t3r;
            x3r = t1r + t3i; x3i = t1i - t3r;
        }
        int idxD = (j / NS) * (NS * 4) + jm;
        dr[PADF(idxD)]          = x0r; di[PADF(idxD)]          = x0i;
        dr[PADF(idxD + NS)]     = x1r; di[PADF(idxD + NS)]     = x1i;
        dr[PADF(idxD + 2 * NS)] = x2r; di[PADF(idxD + 2 * NS)] = x2i;
        dr[PADF(idxD + 3 * NS)] = x3r; di[PADF(idxD + 3 * NS)] = x3i;
    }
}

// 6 radix-4 stages, ping-pong; result lands back in A (natural order, PADF'd).
template<int DIR>
__device__ inline void fft4096(float* Ar, float* Ai, float* Br, float* Bi,
                               const float* twr, const float* twi, int tid) {
    fft_stage<DIR, 1>(Ar, Ai, Br, Bi, twr, twi, tid);    __syncthreads();
    fft_stage<DIR, 4>(Br, Bi, Ar, Ai, twr, twi, tid);    __syncthreads();
    fft_stage<DIR, 16>(Ar, Ai, Br, Bi, twr, twi, tid);   __syncthreads();
    fft_stage<DIR, 64>(Br, Bi, Ar, Ai, twr, twi, tid);   __syncthreads();
    fft_stage<DIR, 256>(Ar, Ai, Br, Bi, twr, twi, tid);  __syncthreads();
    fft_stage<DIR, 1024>(Br, Bi, Ar, Ai, twr, twi, tid); __syncthreads();
}

// Shared post-FFT spectral product + atomic accumulate.
__device__ inline void spd_accum(const float* Ar, const float* Ai,
                                 float* spd_re, float* spd_im, int bh, int tid) {
    float* sre = spd_re + (size_t)bh * 2049u;
    float* sim = spd_im + (size_t)bh * 2049u;
    for (int f = tid; f <= 2048; f += 256) {
        float a1 = Ar[PADF(f)], b1 = Ai[PADF(f)];
        int mm = (4096 - f) & 4095;
        float a2 = Ar[PADF(mm)], b2 = Ai[PADF(mm)];
        // 2Q = (a1+a2) + i(b1-b2); 2conj(K) = (b1+b2) + i(a1-a2)
        float qr = a1 + a2, qi = b1 - b2;
        float kr = b1 + b2, ki = a1 - a2;
        atomicAdd(&sre[f], 0.25f * (qr * kr - qi * ki));
        atomicAdd(&sim[f], 0.25f * (qr * ki + qi * kr));
    }
}

// K1 fast: one block per (b,c), c=h*32+d. Coalesced float2 loads from xT.
__global__ __launch_bounds__(256) void fwd_spd_fast(const float2* __restrict__ xT,
                                                    float* spd_re, float* spd_im,
                                                    const float* __restrict__ twr,
                                                    const float* __restrict__ twi) {
    __shared__ float Ar[NP], Ai[NP], Br[NP], Bi[NP];   // 66 KB
    int bid = blockIdx.x;                 // b*256 + c
    int tid = threadIdx.x;
    const float2* src = xT + (size_t)bid * 4096u;
#pragma unroll
    for (int t = 0; t < 16; ++t) {
        int n = tid + t * 256;
        float2 v = src[n];
        Ar[PADF(n)] = v.x;
        Ai[PADF(n)] = v.y;
    }
    __syncthreads();
    fft4096<-1>(Ar, Ai, Br, Bi, twr, twi, tid);
    spd_accum(Ar, Ai, spd_re, spd_im, bid >> 5, tid);
}

// K1 slow fallback: strided loads straight from q,k (used when ws too small).
__global__ __launch_bounds__(256) void fwd_spd_slow(const float* __restrict__ q,
                                                    const float* __restrict__ k,
                                                    float* spd_re, float* spd_im,
                                                    const float* __restrict__ twr,
                                                    const float* __restrict__ twi) {
    __shared__ float Ar[NP], Ai[NP], Br[NP], Bi[NP];
    int bid = blockIdx.x;                 // b*256 + c
    int b = bid >> 8, c = bid & 255;
    int tid = threadIdx.x;
    size_t base = (size_t)b * 1048576u + (size_t)c;
#pragma unroll
    for (int t = 0; t < 16; ++t) {
        int n = tid + t * 256;
        Ar[PADF(n)] = q[base + (size_t)n * 256u];
        Ai[PADF(n)] = k[base + (size_t)n * 256u];
    }
    __syncthreads();
    fft4096<-1>(Ar, Ai, Br, Bi, twr, twi, tid);
    spd_accum(Ar, Ai, spd_re, spd_im, bid >> 5, tid);
}

// K2: one block per (b,h). Mirror Hermitian spectrum, inverse FFT (x 1/N),
// iterative top-8 argmax (ties -> lowest index), softmax, emit weights+delays.
__global__ __launch_bounds__(256) void ifft_topk_kernel(const float* __restrict__ spd_re,
                                                        const float* __restrict__ spd_im,
                                                        float* __restrict__ wout,
                                                        int* __restrict__ dout,
                                                        const float* __restrict__ twr,
                                                        const float* __restrict__ twi) {
    __shared__ float Ar[NP], Ai[NP], Br[NP], Bi[NP];
    int bh = blockIdx.x;
    int tid = threadIdx.x;
    const float sc = 1.0f / 4096.0f;
    for (int f = tid; f <= 2048; f += 256) {
        float re = spd_re[bh * 2049 + f] * sc;
        float im = spd_im[bh * 2049 + f] * sc;
        Ar[PADF(f)] = re; Ai[PADF(f)] = im;
        if (f > 0 && f < 2048) {
            Ar[PADF(4096 - f)] = re;
            Ai[PADF(4096 - f)] = -im;
        }
    }
    __syncthreads();
    fft4096<1>(Ar, Ai, Br, Bi, twr, twi, tid);
    // corr[tau] = Ar[PADF(tau)]. Scratch aliased into free B buffers (raw idx).
    float* rv   = Br;
    int*   ri   = (int*)Bi;
    float* topv = Br + 512;
    int*   topi = ((int*)Bi) + 512;
    for (int kk = 0; kk < 8; ++kk) {
        float best = -3.0e38f; int bidx = 0;
#pragma unroll
        for (int t = 0; t < 16; ++t) {
            int f = tid + t * 256;
            float val = Ar[PADF(f)];
            if (val > best) { best = val; bidx = f; }   // strict > keeps lowest f
        }
        rv[tid] = best; ri[tid] = bidx;
        __syncthreads();
        for (int off = 128; off > 0; off >>= 1) {
            if (tid < off) {
                float v2 = rv[tid + off]; int i2 = ri[tid + off];
                if (v2 > rv[tid] || (v2 == rv[tid] && i2 < ri[tid])) { rv[tid] = v2; ri[tid] = i2; }
            }
            __syncthreads();
        }
        if (tid == 0) {
            topv[kk] = rv[0]; topi[kk] = ri[0];
            Ar[PADF(ri[0])] = -3.0e38f;                 // remove winner
        }
        __syncthreads();
    }
    if (tid == 0) {
        float mx = topv[0];                             // selected descending
        float e[8], s = 0.0f;
#pragma unroll
        for (int kk = 0; kk < 8; ++kk) { e[kk] = expf(topv[kk] - mx); s += e[kk]; }
        float inv = 1.0f / s;
#pragma unroll
        for (int kk = 0; kk < 8; ++kk) {
            wout[bh * 8 + kk] = e[kk] * inv;
            dout[bh * 8 + kk] = topi[kk];
        }
    }
}

// K3: one block per (b,l); thread = h*32+d. out = sum_k w_k * v[(l+delay_k)%L].
__global__ __launch_bounds__(256) void agg_kernel(const float* __restrict__ v,
                                                  const float* __restrict__ w,
                                                  const int* __restrict__ dl,
                                                  float* __restrict__ out) {
    __shared__ float sw[64];
    __shared__ int   sd[64];
    int blk = blockIdx.x;              // b*4096 + l
    int b = blk >> 12, l = blk & 4095;
    int tid = threadIdx.x;
    if (tid < 64) {
        int h = tid >> 3, kk = tid & 7;
        sw[tid] = w[(b * 8 + h) * 8 + kk];
        sd[tid] = dl[(b * 8 + h) * 8 + kk];
    }
    __syncthreads();
    int h = tid >> 5, d = tid & 31;
    size_t vbase = (size_t)b * 1048576u + (size_t)h * 32u + (size_t)d;
    float acc = 0.0f;
#pragma unroll
    for (int kk = 0; kk < 8; ++kk) {
        float wv = sw[h * 8 + kk];
        int l2 = (l + sd[h * 8 + kk]) & 4095;
        acc += wv * v[vbase + (size_t)l2 * 256u];
    }
    out[(size_t)blk * 256u + tid] = acc;
}

extern "C" void kernel_launch(void* const* d_in, const int* in_sizes, int n_in,
                              void* d_out, int out_size, void* d_ws, size_t ws_size,
                              hipStream_t stream) {
    const float* q = (const float*)d_in[0];
    const float* k = (const float*)d_in[1];
    const float* v = (const float*)d_in[2];
    float* out = (float*)d_out;
    float* ws  = (float*)d_ws;

    // fast path needs: xT (16777216) + spd (2*131136) + w/d (1024) + tw (8192) floats
    const size_t XT_FLOATS = 16777216u;
    const size_t FAST_FLOATS = XT_FLOATS + 2u * 131136u + 1024u + 8192u;
    bool fast = ws_size >= FAST_FLOATS * sizeof(float);

    if (fast) {
        float2* xT    = (float2*)ws;
        float* spd_re = ws + XT_FLOATS;
        float* spd_im = spd_re + 131136;
        float* wbuf   = spd_im + 131136;
        int*   dbuf   = (int*)(wbuf + 512);
        float* twr    = wbuf + 1024;
        float* twi    = twr + 4096;
        hipMemsetAsync((char*)d_ws + XT_FLOATS * sizeof(float), 0,
                       2u * 131136u * sizeof(float), stream);
        twiddle_init_kernel<<<16, 256, 0, stream>>>(twr, twi);
        transpose_pack_kernel<<<2048, 256, 0, stream>>>(q, k, xT);
        fwd_spd_fast<<<2048, 256, 0, stream>>>(xT, spd_re, spd_im, twr, twi);
        ifft_topk_kernel<<<64, 256, 0, stream>>>(spd_re, spd_im, wbuf, dbuf, twr, twi);
        agg_kernel<<<8 * 4096, 256, 0, stream>>>(v, wbuf, dbuf, out);
    } else {
        float* spd_re = ws;
        float* spd_im = spd_re + 131136;
        float* wbuf   = spd_im + 131136;
        int*   dbuf   = (int*)(wbuf + 512);
        float* twr    = wbuf + 1024;
        float* twi    = twr + 4096;
        hipMemsetAsync(d_ws, 0, 2u * 131136u * sizeof(float), stream);
        twiddle_init_kernel<<<16, 256, 0, stream>>>(twr, twi);
        fwd_spd_slow<<<2048, 256, 0, stream>>>(q, k, spd_re, spd_im, twr, twi);
        ifft_topk_kernel<<<64, 256, 0, stream>>>(spd_re, spd_im, wbuf, dbuf, twr, twi);
        agg_kernel<<<8 * 4096, 256, 0, stream>>>(v, wbuf, dbuf, out);
    }
}

// Round 3
// 118.686 us; speedup vs baseline: 1.3884x; 1.1618x over previous
//
#include <hip/hip_runtime.h>
#include <hip/hip_bf16.h>

// AutoCorrelation (Autoformer): FFT-based circular cross-correlation,
// top-8 delays, softmax weights, rolled-value aggregation.
// B=8, L=4096, H=8, D=32, K=8. Layout [B,L,H,D]: idx = b*1048576 + l*256 + h*32 + d.
//
// R2: radix-16 Stockham (3 passes, 16-pt FFT in registers), interleaved-float2
//     LDS with XOR swizzle (conflict-free b64 everywhere), float4 transpose,
//     float4 aggregation.

#define SWZ(i) ((i) ^ (((i) >> 4) & 15))   // float2-index swizzle: pos ^= row&15

__global__ __launch_bounds__(256) void twiddle_init_kernel(float* twr, float* twi) {
    int m = blockIdx.x * 256 + threadIdx.x;             // 16 blocks -> m in [0,4096)
    float ang = 6.2831853071795864769f * (float)m / 4096.0f;
    twr[m] = cosf(ang);
    twi[m] = -sinf(ang);                                // forward twiddle e^{-i*ang}
}

__device__ inline void cmul(float& outr, float& outi, float ar, float ai, float br, float bi) {
    outr = ar * br - ai * bi;
    outi = ar * bi + ai * br;
}

// 16-point DFT in registers. DIR=-1 forward, +1 inverse (no 1/N scale).
template<int DIR>
__device__ inline void fft16(float* vr, float* vi) {
    const float C1 = 0.92387953251128675613f;  // cos(pi/8)
    const float S1 = 0.38268343236508977173f;  // sin(pi/8)
    const float R2 = 0.70710678118654752440f;  // sqrt(2)/2
    float ur[16], ui[16];
    // stage 1: DFT4 over n1 (stride 4), for each n2; u[k1*4+n2]
#pragma unroll
    for (int n2 = 0; n2 < 4; ++n2) {
        float ar = vr[n2],      ai = vi[n2];
        float br = vr[n2 + 4],  bi = vi[n2 + 4];
        float cr = vr[n2 + 8],  ci = vi[n2 + 8];
        float dr = vr[n2 + 12], di = vi[n2 + 12];
        float acr = ar + cr, aci = ai + ci;
        float asr = ar - cr, asi = ai - ci;
        float bdr = br + dr, bdi = bi + di;
        float bsr = br - dr, bsi = bi - di;
        ur[0 + n2]  = acr + bdr; ui[0 + n2]  = aci + bdi;
        ur[8 + n2]  = acr - bdr; ui[8 + n2]  = aci - bdi;
        if (DIR < 0) {   // X1 = as - i*bs ; X3 = as + i*bs
            ur[4 + n2]  = asr + bsi; ui[4 + n2]  = asi - bsr;
            ur[12 + n2] = asr - bsi; ui[12 + n2] = asi + bsr;
        } else {
            ur[4 + n2]  = asr - bsi; ui[4 + n2]  = asi + bsr;
            ur[12 + n2] = asr + bsi; ui[12 + n2] = asi - bsr;
        }
    }
    // twiddle: u[k1*4+n2] *= W16^{DIR*k1*n2}
    // forward (DIR<0): (r,i)*(c - i s) = (r c + i s, i c - r s)
    // inverse:         (r,i)*(c + i s) = (r c - i s, i c + r s)
#pragma unroll
    for (int k1 = 1; k1 < 4; ++k1) {
#pragma unroll
        for (int n2 = 1; n2 < 4; ++n2) {
            int e = k1 * n2;        // in {1,2,3,4,6,9}
            float c, s;
            if (e == 1)      { c = C1;  s = S1; }
            else if (e == 2) { c = R2;  s = R2; }
            else if (e == 3) { c = S1;  s = C1; }
            else if (e == 4) { c = 0.f; s = 1.f; }
            else if (e == 6) { c = -R2; s = R2; }
            else             { c = -C1; s = -S1; }   // e == 9
            int idx = k1 * 4 + n2;
            float r0 = ur[idx], i0 = ui[idx];
            if (DIR < 0) { ur[idx] = r0 * c + i0 * s; ui[idx] = i0 * c - r0 * s; }
            else         { ur[idx] = r0 * c - i0 * s; ui[idx] = i0 * c + r0 * s; }
        }
    }
    // stage 2: DFT4 over n2 for each k1; X[k1 + 4*k2]
#pragma unroll
    for (int k1 = 0; k1 < 4; ++k1) {
        float ar = ur[k1 * 4 + 0], ai = ui[k1 * 4 + 0];
        float br = ur[k1 * 4 + 1], bi = ui[k1 * 4 + 1];
        float cr = ur[k1 * 4 + 2], ci = ui[k1 * 4 + 2];
        float dr = ur[k1 * 4 + 3], di = ui[k1 * 4 + 3];
        float acr = ar + cr, aci = ai + ci;
        float asr = ar - cr, asi = ai - ci;
        float bdr = br + dr, bdi = bi + di;
        float bsr = br - dr, bsi = bi - di;
        vr[k1]      = acr + bdr; vi[k1]      = aci + bdi;
        vr[k1 + 8]  = acr - bdr; vi[k1 + 8]  = aci - bdi;
        if (DIR < 0) {
            vr[k1 + 4]  = asr + bsi; vi[k1 + 4]  = asi - bsr;
            vr[k1 + 12] = asr - bsi; vi[k1 + 12] = asi + bsr;
        } else {
            vr[k1 + 4]  = asr - bsi; vi[k1 + 4]  = asi + bsr;
            vr[k1 + 12] = asr + bsi; vi[k1 + 12] = asi - bsr;
        }
    }
}

// One radix-16 Stockham pass: src -> dst (both swizzled float2 LDS).
// j = tid in [0,256). NS in {1,16,256}.
template<int DIR, int NS>
__device__ inline void fft_pass16(const float2* __restrict__ src, float2* __restrict__ dst,
                                  const float* __restrict__ twr, const float* __restrict__ twi,
                                  int j) {
    float vr[16], vi[16];
#pragma unroll
    for (int r = 0; r < 16; ++r) {
        float2 x = src[SWZ(j + r * 256)];
        vr[r] = x.x; vi[r] = x.y;
    }
    if (NS > 1) {
        int m = (j & (NS - 1)) * (4096 / (16 * NS));
        float w1r = twr[m], w1i = twi[m];
        if (DIR > 0) w1i = -w1i;
        float wr[16], wi[16];
        wr[1] = w1r; wi[1] = w1i;
#pragma unroll
        for (int r = 2; r < 16; ++r)        // log-depth ladder: w^r = w^(r/2) * w^((r+1)/2)
            cmul(wr[r], wi[r], wr[r >> 1], wi[r >> 1], wr[(r + 1) >> 1], wi[(r + 1) >> 1]);
#pragma unroll
        for (int r = 1; r < 16; ++r) {
            float r0 = vr[r], i0 = vi[r];
            vr[r] = r0 * wr[r] - i0 * wi[r];
            vi[r] = r0 * wi[r] + i0 * wr[r];
        }
    }
    fft16<DIR>(vr, vi);
    int base = (j / NS) * (16 * NS) + (j & (NS - 1));
#pragma unroll
    for (int r = 0; r < 16; ++r)
        dst[SWZ(base + r * NS)] = make_float2(vr[r], vi[r]);
}

// 3 passes: A -> B -> A -> B. Result lands in B, natural order (swizzled).
template<int DIR>
__device__ inline void fft4096(float2* A, float2* Bu,
                               const float* twr, const float* twi, int tid) {
    fft_pass16<DIR, 1>(A, Bu, twr, twi, tid);    __syncthreads();
    fft_pass16<DIR, 16>(Bu, A, twr, twi, tid);   __syncthreads();
    fft_pass16<DIR, 256>(A, Bu, twr, twi, tid);  __syncthreads();
}

// Transpose+pack: q,k [B, L, 256] -> xT[b, c, l] = float2(q, k), c = h*32+d.
// 64(l) x 64(c) tiles; float4 global loads; float4 stores (2 l per thread).
__global__ __launch_bounds__(256) void transpose_pack_kernel(const float4* __restrict__ q4,
                                                             const float4* __restrict__ k4,
                                                             float4* __restrict__ xT4) {
    __shared__ float qs[64][65];
    __shared__ float ks[64][65];
    int bid = blockIdx.x;             // b*256 + lt*4 + ct
    int ct = bid & 3;
    int lt = (bid >> 2) & 63;
    int b  = bid >> 8;
    int tid = threadIdx.x;
    int l0 = lt * 64, c0 = ct * 64;
    int cw = tid & 15;                // float4 index within tile (16 * 4 = 64 c)
    int rr = tid >> 4;                // 16 rows per iter
#pragma unroll
    for (int it = 0; it < 4; ++it) {
        int row = it * 16 + rr;       // l_local
        size_t g = (size_t)(b * 4096 + l0 + row) * 64u + (size_t)(c0 / 4 + cw);
        float4 qv = q4[g];
        float4 kv = k4[g];
        qs[row][cw * 4 + 0] = qv.x; qs[row][cw * 4 + 1] = qv.y;
        qs[row][cw * 4 + 2] = qv.z; qs[row][cw * 4 + 3] = qv.w;
        ks[row][cw * 4 + 0] = kv.x; ks[row][cw * 4 + 1] = kv.y;
        ks[row][cw * 4 + 2] = kv.z; ks[row][cw * 4 + 3] = kv.w;
    }
    __syncthreads();
    int a = tid & 31;                 // l-pair index (2 l per thread)
    int cb = tid >> 5;                // 8 c per iter
#pragma unroll
    for (int it = 0; it < 8; ++it) {
        int cc = it * 8 + cb;         // c_local
        float4 o;
        o.x = qs[2 * a][cc];     o.y = ks[2 * a][cc];
        o.z = qs[2 * a + 1][cc]; o.w = ks[2 * a + 1][cc];
        xT4[(size_t)(b * 256 + c0 + cc) * 2048u + (size_t)(l0 / 2 + a)] = o;
    }
}

// Shared post-FFT spectral product + atomic accumulate (Z = FFT(q + i k) in Bu).
__device__ inline void spd_accum(const float2* Bu, float* spd_re, float* spd_im,
                                 int bh, int tid) {
    float* sre = spd_re + (size_t)bh * 2049u;
    float* sim = spd_im + (size_t)bh * 2049u;
    for (int f = tid; f <= 2048; f += 256) {
        float2 z1 = Bu[SWZ(f)];
        float2 z2 = Bu[SWZ((4096 - f) & 4095)];
        // 2Q = (z1.x+z2.x) + i(z1.y-z2.y); 2conj(K) = (z1.y+z2.y) + i(z1.x-z2.x)
        float qr = z1.x + z2.x, qi = z1.y - z2.y;
        float kr = z1.y + z2.y, ki = z1.x - z2.x;
        atomicAdd(&sre[f], 0.25f * (qr * kr - qi * ki));
        atomicAdd(&sim[f], 0.25f * (qr * ki + qi * kr));
    }
}

// K1 fast: one block per (b,c), c=h*32+d. Coalesced float2 loads from xT.
__global__ __launch_bounds__(256) void fwd_spd_fast(const float2* __restrict__ xT,
                                                    float* spd_re, float* spd_im,
                                                    const float* __restrict__ twr,
                                                    const float* __restrict__ twi) {
    __shared__ float2 A[4096], Bu[4096];   // 64 KB
    int bid = blockIdx.x;                  // b*256 + c
    int tid = threadIdx.x;
    const float2* src = xT + (size_t)bid * 4096u;
#pragma unroll
    for (int t = 0; t < 16; ++t) {
        int n = tid + t * 256;
        A[SWZ(n)] = src[n];
    }
    __syncthreads();
    fft4096<-1>(A, Bu, twr, twi, tid);
    spd_accum(Bu, spd_re, spd_im, bid >> 5, tid);
}

// K1 slow fallback: strided loads straight from q,k (used when ws too small).
__global__ __launch_bounds__(256) void fwd_spd_slow(const float* __restrict__ q,
                                                    const float* __restrict__ k,
                                                    float* spd_re, float* spd_im,
                                                    const float* __restrict__ twr,
                                                    const float* __restrict__ twi) {
    __shared__ float2 A[4096], Bu[4096];
    int bid = blockIdx.x;                 // b*256 + c
    int b = bid >> 8, c = bid & 255;
    int tid = threadIdx.x;
    size_t base = (size_t)b * 1048576u + (size_t)c;
#pragma unroll
    for (int t = 0; t < 16; ++t) {
        int n = tid + t * 256;
        A[SWZ(n)] = make_float2(q[base + (size_t)n * 256u], k[base + (size_t)n * 256u]);
    }
    __syncthreads();
    fft4096<-1>(A, Bu, twr, twi, tid);
    spd_accum(Bu, spd_re, spd_im, bid >> 5, tid);
}

// K2: one block per (b,h). Mirror Hermitian spectrum, inverse FFT (x 1/N),
// iterative top-8 argmax (ties -> lowest index), softmax, emit weights+delays.
__global__ __launch_bounds__(256) void ifft_topk_kernel(const float* __restrict__ spd_re,
                                                        const float* __restrict__ spd_im,
                                                        float* __restrict__ wout,
                                                        int* __restrict__ dout,
                                                        const float* __restrict__ twr,
                                                        const float* __restrict__ twi) {
    __shared__ float2 A[4096], Bu[4096];
    __shared__ float rv[256], topv[8];
    __shared__ int   ri[256], topi[8];
    int bh = blockIdx.x;
    int tid = threadIdx.x;
    const float sc = 1.0f / 4096.0f;
    for (int f = tid; f <= 2048; f += 256) {
        float re = spd_re[bh * 2049 + f] * sc;
        float im = spd_im[bh * 2049 + f] * sc;
        A[SWZ(f)] = make_float2(re, im);
        if (f > 0 && f < 2048) A[SWZ(4096 - f)] = make_float2(re, -im);
    }
    __syncthreads();
    fft4096<1>(A, Bu, twr, twi, tid);
    // corr[tau] = Bu[SWZ(tau)].x
    for (int kk = 0; kk < 8; ++kk) {
        float best = -3.0e38f; int bidx = 0;
#pragma unroll
        for (int t = 0; t < 16; ++t) {
            int f = tid + t * 256;
            float val = Bu[SWZ(f)].x;
            if (val > best) { best = val; bidx = f; }   // strict > keeps lowest f
        }
        rv[tid] = best; ri[tid] = bidx;
        __syncthreads();
        for (int off = 128; off > 0; off >>= 1) {
            if (tid < off) {
                float v2 = rv[tid + off]; int i2 = ri[tid + off];
                if (v2 > rv[tid] || (v2 == rv[tid] && i2 < ri[tid])) { rv[tid] = v2; ri[tid] = i2; }
            }
            __syncthreads();
        }
        if (tid == 0) {
            topv[kk] = rv[0]; topi[kk] = ri[0];
            Bu[SWZ(ri[0])].x = -3.0e38f;                // remove winner
        }
        __syncthreads();
    }
    if (tid == 0) {
        float mx = topv[0];                             // selected descending
        float e[8], s = 0.0f;
#pragma unroll
        for (int kk = 0; kk < 8; ++kk) { e[kk] = expf(topv[kk] - mx); s += e[kk]; }
        float inv = 1.0f / s;
#pragma unroll
        for (int kk = 0; kk < 8; ++kk) {
            wout[bh * 8 + kk] = e[kk] * inv;
            dout[bh * 8 + kk] = topi[kk];
        }
    }
}

// K3: one block per 4 l's; thread = (lq, c4). out = sum_k w_k * v[(l+delay_k)%L].
__global__ __launch_bounds__(256) void agg_kernel(const float4* __restrict__ v4,
                                                  const float* __restrict__ w,
                                                  const int* __restrict__ dl,
                                                  float4* __restrict__ out4) {
    __shared__ float sw[64];
    __shared__ int   sd[64];
    int blk = blockIdx.x;              // b*1024 + lg
    int b = blk >> 10, lg = blk & 1023;
    int tid = threadIdx.x;
    if (tid < 64) {
        int h = tid >> 3, kk = tid & 7;
        sw[tid] = w[(b * 8 + h) * 8 + kk];
        sd[tid] = dl[(b * 8 + h) * 8 + kk];
    }
    __syncthreads();
    int lq = tid >> 6;                 // 0..3
    int c4 = tid & 63;                 // float4 index over 256 floats
    int h  = c4 >> 3;
    int l  = lg * 4 + lq;
    float4 acc = make_float4(0.f, 0.f, 0.f, 0.f);
#pragma unroll
    for (int kk = 0; kk < 8; ++kk) {
        float wv = sw[h * 8 + kk];
        int l2 = (l + sd[h * 8 + kk]) & 4095;
        float4 x = v4[(size_t)(b * 4096 + l2) * 64u + (size_t)c4];
        acc.x += wv * x.x; acc.y += wv * x.y;
        acc.z += wv * x.z; acc.w += wv * x.w;
    }
    out4[(size_t)(b * 4096 + l) * 64u + (size_t)c4] = acc;
}

extern "C" void kernel_launch(void* const* d_in, const int* in_sizes, int n_in,
                              void* d_out, int out_size, void* d_ws, size_t ws_size,
                              hipStream_t stream) {
    const float* q = (const float*)d_in[0];
    const float* k = (const float*)d_in[1];
    const float* v = (const float*)d_in[2];
    float* ws  = (float*)d_ws;

    // fast path needs: xT (16777216) + spd (2*131136) + w/d (1024) + tw (8192) floats
    const size_t XT_FLOATS = 16777216u;
    const size_t FAST_FLOATS = XT_FLOATS + 2u * 131136u + 1024u + 8192u;
    bool fast = ws_size >= FAST_FLOATS * sizeof(float);

    if (fast) {
        float* spd_re = ws + XT_FLOATS;
        float* spd_im = spd_re + 131136;
        float* wbuf   = spd_im + 131136;
        int*   dbuf   = (int*)(wbuf + 512);
        float* twr    = wbuf + 1024;
        float* twi    = twr + 4096;
        hipMemsetAsync((char*)d_ws + XT_FLOATS * sizeof(float), 0,
                       2u * 131136u * sizeof(float), stream);
        twiddle_init_kernel<<<16, 256, 0, stream>>>(twr, twi);
        transpose_pack_kernel<<<2048, 256, 0, stream>>>((const float4*)q, (const float4*)k,
                                                        (float4*)ws);
        fwd_spd_fast<<<2048, 256, 0, stream>>>((const float2*)ws, spd_re, spd_im, twr, twi);
        ifft_topk_kernel<<<64, 256, 0, stream>>>(spd_re, spd_im, wbuf, dbuf, twr, twi);
        agg_kernel<<<8 * 1024, 256, 0, stream>>>((const float4*)v, wbuf, dbuf, (float4*)d_out);
    } else {
        float* spd_re = ws;
        float* spd_im = spd_re + 131136;
        float* wbuf   = spd_im + 131136;
        int*   dbuf   = (int*)(wbuf + 512);
        float* twr    = wbuf + 1024;
        float* twi    = twr + 4096;
        hipMemsetAsync(d_ws, 0, 2u * 131136u * sizeof(float), stream);
        twiddle_init_kernel<<<16, 256, 0, stream>>>(twr, twi);
        fwd_spd_slow<<<2048, 256, 0, stream>>>(q, k, spd_re, spd_im, twr, twi);
        ifft_topk_kernel<<<64, 256, 0, stream>>>(spd_re, spd_im, wbuf, dbuf, twr, twi);
        agg_kernel<<<8 * 1024, 256, 0, stream>>>((const float4*)v, wbuf, dbuf, (float4*)d_out);
    }
}